// Round 4
// baseline (507.409 us; speedup 1.0000x reference)
//
#include <hip/hip_runtime.h>
#include <math.h>

#define NUM_CLASSES 26
#define HH 512
#define WW 512
#define NB 4
#define PHH 171
#define PWW 171
#define NHH 169
#define NWW 169
#define MPTS (NHH*NWW)        // 28561
#define NCT (NB*NUM_CLASSES)  // 104
#define CLIPV 1e-6f
#define PSTR 176              // padded pool row stride (16B-aligned float4 rows)
#define NCHUNK 4
#define ROWS_PER_CHUNK 43     // ceil(169/4)
#define NSLOT 189             // 45 covL + 45 covP + 81 covLP + 9 sumL + 9 sumP

// ---------- Kernel A: vertical 3-row max of (m ? x : -inf) and (t*m) ----------
// One thread per (nc, ph, 4-col segment). Fully coalesced float4 I/O, no LDS.
__global__ __launch_bounds__(256) void vpool_kernel(const float* __restrict__ cls,
        const float* __restrict__ tgt, const float* __restrict__ mask,
        float* __restrict__ aV, unsigned int* __restrict__ bV) {
    int idx = blockIdx.x * 256 + threadIdx.x;
    if (idx >= NCT * PHH * 128) return;
    int seg = idx & 127;
    int t   = idx >> 7;
    int ph  = t % PHH;
    int nc  = t / PHH;
    int n   = nc / NUM_CLASSES;

    const float4* c4p = (const float4*)(cls  + (size_t)nc * HH * WW);
    const float4* t4p = (const float4*)(tgt  + (size_t)nc * HH * WW);
    const float4* m4p = (const float4*)(mask + (size_t)n  * HH * WW);

    float a0 = -INFINITY, a1 = -INFINITY, a2 = -INFINITY, a3 = -INFINITY;
    float b0 = 0.f, b1 = 0.f, b2 = 0.f, b3 = 0.f;

    const int r0 = 3 * ph - 1;
    const int s0 = (ph == 0) ? 1 : 0;   // only ph==0 has an out-of-range row (r=-1)
    for (int s = s0; s < 3; ++s) {
        int r = r0 + s;
        float4 c = c4p[r * 128 + seg];
        float4 g = t4p[r * 128 + seg];
        float4 m = m4p[r * 128 + seg];
        a0 = fmaxf(a0, m.x > 0.5f ? c.x : -INFINITY);
        a1 = fmaxf(a1, m.y > 0.5f ? c.y : -INFINITY);
        a2 = fmaxf(a2, m.z > 0.5f ? c.z : -INFINITY);
        a3 = fmaxf(a3, m.w > 0.5f ? c.w : -INFINITY);
        b0 = fmaxf(b0, g.x * m.x);
        b1 = fmaxf(b1, g.y * m.y);
        b2 = fmaxf(b2, g.z * m.z);
        b3 = fmaxf(b3, g.w * m.w);
    }
    ((float4*)aV)[idx] = make_float4(a0, a1, a2, a3);
    unsigned int pb = (b0 > 0.5f ? 1u : 0u) | (b1 > 0.5f ? 1u : 0u) << 8 |
                      (b2 > 0.5f ? 1u : 0u) << 16 | (b3 > 0.5f ? 1u : 0u) << 24;
    bV[idx] = pb;
}

// ---------- Kernel B: horizontal stride-3 max + deferred sigmoid ----------
__global__ __launch_bounds__(256) void hpool_kernel(const float* __restrict__ aV,
        const unsigned char* __restrict__ bV,
        float* __restrict__ poolL, float* __restrict__ poolP) {
    int idx = blockIdx.x * 256 + threadIdx.x;
    if (idx >= NCT * PHH * PWW) return;
    int pw = idx % PWW;
    int t  = idx / PWW;
    int ph = t % PHH;
    int nc = t / PHH;

    const float*         ar = aV + (size_t)(nc * PHH + ph) * WW;
    const unsigned char* br = bV + (size_t)(nc * PHH + ph) * WW;

    int c0 = 3 * pw - 1;
    float a = -INFINITY;
    int   b = 0;
    #pragma unroll
    for (int dc = 0; dc < 3; ++dc) {
        int c = c0 + dc;                 // c <= 511 always; c<0 only for pw==0
        if (c >= 0) {
            a = fmaxf(a, ar[c]);
            b = max(b, (int)br[c]);
        }
    }
    // a == -inf (fully masked window) -> sigmoid -> 0 -> P = CLIP (matches ref)
    float P = __fdividef(1.0f, 1.0f + __expf(-a)) + CLIPV;
    size_t o = (size_t)(nc * PHH + ph) * PSTR + pw;
    poolP[o] = P;
    poolL[o] = (float)b;
}

// ---------- Kernel C: covariance raw-sum partials, float4-vectorized ----------
// grid (NCT, 3 modes, NCHUNK row-chunks). partial layout: [ch][slot][NCT] (coalesced for solve)
__global__ __launch_bounds__(256) void cov_kernel(const float* __restrict__ poolL,
        const float* __restrict__ poolP, float* __restrict__ partial) {
    const int nc = blockIdx.x, mode = blockIdx.y, ch = blockIdx.z;
    const int tid = threadIdx.x, lane = tid & 63, wave = tid >> 6;
    const int rowbase = ch * ROWS_PER_CHUNK;
    const int rc = (rowbase + ROWS_PER_CHUNK <= NHH) ? ROWS_PER_CHUNK : (NHH - rowbase);
    const float* Lb = poolL + (size_t)nc * PHH * PSTR;
    const float* Pb = poolP + (size_t)nc * PHH * PSTR;

    __shared__ float red[4][81];

    if (mode < 2) {
        const float* src = mode ? Pb : Lb;
        float acc[45], sm[9];
        #pragma unroll
        for (int k = 0; k < 45; ++k) acc[k] = 0.f;
        #pragma unroll
        for (int k = 0; k < 9; ++k) sm[k] = 0.f;

        const int items = rc * 43;
        for (int it = tid; it < items; it += 256) {
            int i  = rowbase + it / 43;
            int g  = it - (it / 43) * 43;
            int j0 = g * 4;
            const float* rp = src + (size_t)i * PSTR + j0;
            float4 x0 = *(const float4*)(rp);
            float4 x1 = *(const float4*)(rp + 4);
            float4 y0 = *(const float4*)(rp + PSTR);
            float4 y1 = *(const float4*)(rp + PSTR + 4);
            float4 z0 = *(const float4*)(rp + 2 * PSTR);
            float4 z1 = *(const float4*)(rp + 2 * PSTR + 4);
            float r0[8] = {x0.x, x0.y, x0.z, x0.w, x1.x, x1.y, x1.z, x1.w};
            float r1[8] = {y0.x, y0.y, y0.z, y0.w, y1.x, y1.y, y1.z, y1.w};
            float r2[8] = {z0.x, z0.y, z0.z, z0.w, z1.x, z1.y, z1.z, z1.w};
            #pragma unroll
            for (int q = 0; q < 4; ++q) {
                float sel = (j0 + q < NWW) ? 1.f : 0.f;
                float v[9], vs[9];
                v[0] = r0[q]; v[1] = r0[q + 1]; v[2] = r0[q + 2];
                v[3] = r1[q]; v[4] = r1[q + 1]; v[5] = r1[q + 2];
                v[6] = r2[q]; v[7] = r2[q + 1]; v[8] = r2[q + 2];
                #pragma unroll
                for (int d = 0; d < 9; ++d) { vs[d] = v[d] * sel; sm[d] += vs[d]; }
                int k = 0;
                #pragma unroll
                for (int d = 0; d < 9; ++d)
                    #pragma unroll
                    for (int e = d; e < 9; ++e)
                        acc[k++] += vs[d] * v[e];
            }
        }
        #pragma unroll
        for (int k = 0; k < 45; ++k) {
            float x = acc[k];
            #pragma unroll
            for (int off = 32; off > 0; off >>= 1) x += __shfl_down(x, off);
            if (lane == 0) red[wave][k] = x;
        }
        float sred[9];
        #pragma unroll
        for (int k = 0; k < 9; ++k) {
            float x = sm[k];
            #pragma unroll
            for (int off = 32; off > 0; off >>= 1) x += __shfl_down(x, off);
            sred[k] = x;
        }
        if (lane == 0) {
            #pragma unroll
            for (int k = 0; k < 9; ++k) red[wave][45 + k] = sred[k];
        }
        __syncthreads();
        if (tid < 54) {
            float x = red[0][tid] + red[1][tid] + red[2][tid] + red[3][tid];
            int slot;
            if (tid < 45) slot = (mode == 0 ? 0 : 45) + tid;
            else          slot = (mode == 0 ? 171 : 180) + (tid - 45);
            partial[((size_t)ch * NSLOT + slot) * NCT + nc] = x;
        }
    } else {
        float acc[81];
        #pragma unroll
        for (int k = 0; k < 81; ++k) acc[k] = 0.f;

        const int items = rc * 43;
        for (int it = tid; it < items; it += 256) {
            int i  = rowbase + it / 43;
            int g  = it - (it / 43) * 43;
            int j0 = g * 4;
            const float* lp = Lb + (size_t)i * PSTR + j0;
            const float* pp = Pb + (size_t)i * PSTR + j0;
            float4 lx0 = *(const float4*)(lp);
            float4 lx1 = *(const float4*)(lp + 4);
            float4 ly0 = *(const float4*)(lp + PSTR);
            float4 ly1 = *(const float4*)(lp + PSTR + 4);
            float4 lz0 = *(const float4*)(lp + 2 * PSTR);
            float4 lz1 = *(const float4*)(lp + 2 * PSTR + 4);
            float4 px0 = *(const float4*)(pp);
            float4 px1 = *(const float4*)(pp + 4);
            float4 py0 = *(const float4*)(pp + PSTR);
            float4 py1 = *(const float4*)(pp + PSTR + 4);
            float4 pz0 = *(const float4*)(pp + 2 * PSTR);
            float4 pz1 = *(const float4*)(pp + 2 * PSTR + 4);
            float lr0[8] = {lx0.x, lx0.y, lx0.z, lx0.w, lx1.x, lx1.y, lx1.z, lx1.w};
            float lr1[8] = {ly0.x, ly0.y, ly0.z, ly0.w, ly1.x, ly1.y, ly1.z, ly1.w};
            float lr2[8] = {lz0.x, lz0.y, lz0.z, lz0.w, lz1.x, lz1.y, lz1.z, lz1.w};
            float pr0[8] = {px0.x, px0.y, px0.z, px0.w, px1.x, px1.y, px1.z, px1.w};
            float pr1[8] = {py0.x, py0.y, py0.z, py0.w, py1.x, py1.y, py1.z, py1.w};
            float pr2[8] = {pz0.x, pz0.y, pz0.z, pz0.w, pz1.x, pz1.y, pz1.z, pz1.w};
            #pragma unroll
            for (int q = 0; q < 4; ++q) {
                float sel = (j0 + q < NWW) ? 1.f : 0.f;
                float vl[9], vp[9];
                vl[0] = lr0[q] * sel; vl[1] = lr0[q + 1] * sel; vl[2] = lr0[q + 2] * sel;
                vl[3] = lr1[q] * sel; vl[4] = lr1[q + 1] * sel; vl[5] = lr1[q + 2] * sel;
                vl[6] = lr2[q] * sel; vl[7] = lr2[q + 1] * sel; vl[8] = lr2[q + 2] * sel;
                vp[0] = pr0[q]; vp[1] = pr0[q + 1]; vp[2] = pr0[q + 2];
                vp[3] = pr1[q]; vp[4] = pr1[q + 1]; vp[5] = pr1[q + 2];
                vp[6] = pr2[q]; vp[7] = pr2[q + 1]; vp[8] = pr2[q + 2];
                #pragma unroll
                for (int d = 0; d < 9; ++d)
                    #pragma unroll
                    for (int e = 0; e < 9; ++e)
                        acc[d * 9 + e] += vl[d] * vp[e];
            }
        }
        #pragma unroll
        for (int k = 0; k < 81; ++k) {
            float x = acc[k];
            #pragma unroll
            for (int off = 32; off > 0; off >>= 1) x += __shfl_down(x, off);
            if (lane == 0) red[wave][k] = x;
        }
        __syncthreads();
        // BUGFIX (round 3): was `wave==0 && lane<81` but lane<=63, so slots 64..80
        // were never written (poison). Use tid across waves like round 2.
        if (tid < 81) {
            float x = red[0][tid] + red[1][tid] + red[2][tid] + red[3][tid];
            partial[((size_t)ch * NSLOT + 90 + tid) * NCT + nc] = x;
        }
    }
}

// ---------- Kernel D: chunk-sum (coalesced) + 9x9 algebra + reduction ----------
__global__ __launch_bounds__(128) void solve_kernel(const float* __restrict__ partial,
                                                    float* __restrict__ out) {
    int t = threadIdx.x;
    double r = 0.0;
    if (t < NCT) {
        double cl[45], cp[45], clp[81], sL[9], sP[9];
        for (int k = 0; k < 45; ++k) { cl[k] = 0.0; cp[k] = 0.0; }
        for (int k = 0; k < 81; ++k) clp[k] = 0.0;
        for (int k = 0; k < 9; ++k)  { sL[k] = 0.0; sP[k] = 0.0; }
        for (int ch = 0; ch < NCHUNK; ++ch) {
            const float* q = partial + (size_t)ch * NSLOT * NCT;
            for (int k = 0; k < 45; ++k) { cl[k] += q[k * NCT + t]; cp[k] += q[(45 + k) * NCT + t]; }
            for (int k = 0; k < 81; ++k) clp[k] += q[(90 + k) * NCT + t];
            for (int k = 0; k < 9; ++k)  { sL[k] += q[(171 + k) * NCT + t]; sP[k] += q[(180 + k) * NCT + t]; }
        }
        const double M = (double)MPTS;
        double All[9][9], C[9][9], Pm[9][9];
        {
            int k = 0;
            for (int d = 0; d < 9; ++d)
                for (int e = d; e < 9; ++e) {
                    double v = cl[k] - sL[d] * sL[e] / M;
                    All[d][e] = v; All[e][d] = v;
                    double w = cp[k] - sP[d] * sP[e] / M;
                    C[d][e] = w; C[e][d] = w;
                    ++k;
                }
            for (int d = 0; d < 9; ++d)
                for (int e = 0; e < 9; ++e)
                    Pm[d][e] = clp[d * 9 + e] - sL[d] * sP[e] / M;
            for (int d = 0; d < 9; ++d) C[d][d] += 1e-3;
        }
        for (int i = 0; i < 9; ++i) {
            for (int j = 0; j < i; ++j) {
                double sum = C[i][j];
                for (int k2 = 0; k2 < j; ++k2) sum -= C[i][k2] * C[j][k2];
                C[i][j] = sum / C[j][j];
            }
            double sum = C[i][i];
            for (int k2 = 0; k2 < i; ++k2) sum -= C[i][k2] * C[i][k2];
            C[i][i] = sqrt(fmax(sum, 1e-30));
        }
        double X[9][9];
        for (int d = 0; d < 9; ++d) {
            for (int e = 0; e < 9; ++e) {
                double sum = Pm[d][e];
                for (int k2 = 0; k2 < e; ++k2) sum -= C[e][k2] * X[k2][d];
                X[e][d] = sum / C[e][e];
            }
        }
        double A[9][9];
        for (int d = 0; d < 9; ++d)
            for (int g = d; g < 9; ++g) {
                double w = 0.0;
                for (int e = 0; e < 9; ++e) w += X[e][d] * X[e][g];
                double v = All[d][g] - w;
                A[d][g] = v; A[g][d] = v;
            }
        for (int d = 0; d < 9; ++d) A[d][d] += 1e-3;
        for (int i = 0; i < 9; ++i) {
            for (int j = 0; j < i; ++j) {
                double sum = A[i][j];
                for (int k2 = 0; k2 < j; ++k2) sum -= A[i][k2] * A[j][k2];
                A[i][j] = sum / A[j][j];
            }
            double sum = A[i][i];
            for (int k2 = 0; k2 < i; ++k2) sum -= A[i][k2] * A[i][k2];
            A[i][i] = sqrt(fmax(sum, 0.0));
            r += log(A[i][i] + 1e-8);
        }
    }
    __shared__ double red[128];
    red[t] = r;
    __syncthreads();
    for (int s = 64; s > 0; s >>= 1) {
        if (t < s) red[t] += red[t + s];
        __syncthreads();
    }
    if (t == 0) out[0] = (float)(red[0] / 36.0);
}

extern "C" void kernel_launch(void* const* d_in, const int* in_sizes, int n_in,
                              void* d_out, int out_size, void* d_ws, size_t ws_size,
                              hipStream_t stream) {
    const float* cls  = (const float*)d_in[0];
    const float* tgt  = (const float*)d_in[1];
    const float* mask = (const float*)d_in[2];

    float* ws = (float*)d_ws;
    float*        aV      = ws;                                          // 104*171*512 f32
    unsigned int* bV      = (unsigned int*)(aV + (size_t)NCT * PHH * WW);// 104*171*512 u8 (as u32 words)
    float*        poolL   = (float*)((char*)bV + (size_t)NCT * PHH * WW);
    float*        poolP   = poolL + (size_t)NCT * PHH * PSTR;
    float*        partial = poolP + (size_t)NCT * PHH * PSTR;            // NCHUNK*189*104

    const int nA = NCT * PHH * 128;
    vpool_kernel<<<(nA + 255) / 256, 256, 0, stream>>>(cls, tgt, mask, aV, bV);

    const int nB = NCT * PHH * PWW;
    hpool_kernel<<<(nB + 255) / 256, 256, 0, stream>>>(aV, (const unsigned char*)bV, poolL, poolP);

    dim3 gcov(NCT, 3, NCHUNK);
    cov_kernel<<<gcov, 256, 0, stream>>>(poolL, poolP, partial);

    solve_kernel<<<1, 128, 0, stream>>>(partial, (float*)d_out);
}

// Round 5
// 363.445 us; speedup vs baseline: 1.3961x; 1.3961x over previous
//
#include <hip/hip_runtime.h>
#include <math.h>

#define NUM_CLASSES 26
#define HH 512
#define WW 512
#define NB 4
#define PHH 171
#define PWW 171
#define NHH 169
#define NWW 169
#define MPTS (NHH*NWW)        // 28561
#define NCT (NB*NUM_CLASSES)  // 104
#define CLIPV 1e-6f
#define PSTR 176              // padded pool row stride (16B-aligned float4 rows)
#define NCHUNK 8
#define ROWS_PER_CHUNK 22     // ceil(169/8)
#define NSLOT 189             // 45 covL + 45 covP + 81 covLP + 9 sumL + 9 sumP

// ---------- Kernel A: vertical 3-row max of (m ? x : -inf) and (t*m) ----------
__global__ __launch_bounds__(256) void vpool_kernel(const float* __restrict__ cls,
        const float* __restrict__ tgt, const float* __restrict__ mask,
        float* __restrict__ aV, unsigned int* __restrict__ bV) {
    int idx = blockIdx.x * 256 + threadIdx.x;
    if (idx >= NCT * PHH * 128) return;
    int seg = idx & 127;
    int t   = idx >> 7;
    int ph  = t % PHH;
    int nc  = t / PHH;
    int n   = nc / NUM_CLASSES;

    const float4* c4p = (const float4*)(cls  + (size_t)nc * HH * WW);
    const float4* t4p = (const float4*)(tgt  + (size_t)nc * HH * WW);
    const float4* m4p = (const float4*)(mask + (size_t)n  * HH * WW);

    float a0 = -INFINITY, a1 = -INFINITY, a2 = -INFINITY, a3 = -INFINITY;
    float b0 = 0.f, b1 = 0.f, b2 = 0.f, b3 = 0.f;

    const int r0 = 3 * ph - 1;
    const int s0 = (ph == 0) ? 1 : 0;
    for (int s = s0; s < 3; ++s) {
        int r = r0 + s;
        float4 c = c4p[r * 128 + seg];
        float4 g = t4p[r * 128 + seg];
        float4 m = m4p[r * 128 + seg];
        a0 = fmaxf(a0, m.x > 0.5f ? c.x : -INFINITY);
        a1 = fmaxf(a1, m.y > 0.5f ? c.y : -INFINITY);
        a2 = fmaxf(a2, m.z > 0.5f ? c.z : -INFINITY);
        a3 = fmaxf(a3, m.w > 0.5f ? c.w : -INFINITY);
        b0 = fmaxf(b0, g.x * m.x);
        b1 = fmaxf(b1, g.y * m.y);
        b2 = fmaxf(b2, g.z * m.z);
        b3 = fmaxf(b3, g.w * m.w);
    }
    ((float4*)aV)[idx] = make_float4(a0, a1, a2, a3);
    unsigned int pb = (b0 > 0.5f ? 1u : 0u) | (b1 > 0.5f ? 1u : 0u) << 8 |
                      (b2 > 0.5f ? 1u : 0u) << 16 | (b3 > 0.5f ? 1u : 0u) << 24;
    bV[idx] = pb;
}

// ---------- Kernel B: horizontal stride-3 max + deferred sigmoid ----------
__global__ __launch_bounds__(256) void hpool_kernel(const float* __restrict__ aV,
        const unsigned char* __restrict__ bV,
        float* __restrict__ poolL, float* __restrict__ poolP) {
    int idx = blockIdx.x * 256 + threadIdx.x;
    if (idx >= NCT * PHH * PWW) return;
    int pw = idx % PWW;
    int t  = idx / PWW;
    int ph = t % PHH;
    int nc = t / PHH;

    const float*         ar = aV + (size_t)(nc * PHH + ph) * WW;
    const unsigned char* br = bV + (size_t)(nc * PHH + ph) * WW;

    int c0 = 3 * pw - 1;
    float a = -INFINITY;
    int   b = 0;
    #pragma unroll
    for (int dc = 0; dc < 3; ++dc) {
        int c = c0 + dc;
        if (c >= 0) {
            a = fmaxf(a, ar[c]);
            b = max(b, (int)br[c]);
        }
    }
    float P = __fdividef(1.0f, 1.0f + __expf(-a)) + CLIPV;
    size_t o = (size_t)(nc * PHH + ph) * PSTR + pw;
    poolP[o] = P;
    poolL[o] = (float)b;
}

// ---------- Kernel C: covariance raw-sum partials, float4-vectorized ----------
__global__ __launch_bounds__(256) void cov_kernel(const float* __restrict__ poolL,
        const float* __restrict__ poolP, float* __restrict__ partial) {
    const int nc = blockIdx.x, mode = blockIdx.y, ch = blockIdx.z;
    const int tid = threadIdx.x, lane = tid & 63, wave = tid >> 6;
    const int rowbase = ch * ROWS_PER_CHUNK;
    const int rc = (rowbase + ROWS_PER_CHUNK <= NHH) ? ROWS_PER_CHUNK : (NHH - rowbase);
    const float* Lb = poolL + (size_t)nc * PHH * PSTR;
    const float* Pb = poolP + (size_t)nc * PHH * PSTR;

    __shared__ float red[4][81];

    if (mode < 2) {
        const float* src = mode ? Pb : Lb;
        float acc[45], sm[9];
        #pragma unroll
        for (int k = 0; k < 45; ++k) acc[k] = 0.f;
        #pragma unroll
        for (int k = 0; k < 9; ++k) sm[k] = 0.f;

        const int items = rc * 43;
        for (int it = tid; it < items; it += 256) {
            int i  = rowbase + it / 43;
            int g  = it - (it / 43) * 43;
            int j0 = g * 4;
            const float* rp = src + (size_t)i * PSTR + j0;
            float4 x0 = *(const float4*)(rp);
            float4 x1 = *(const float4*)(rp + 4);
            float4 y0 = *(const float4*)(rp + PSTR);
            float4 y1 = *(const float4*)(rp + PSTR + 4);
            float4 z0 = *(const float4*)(rp + 2 * PSTR);
            float4 z1 = *(const float4*)(rp + 2 * PSTR + 4);
            float r0[8] = {x0.x, x0.y, x0.z, x0.w, x1.x, x1.y, x1.z, x1.w};
            float r1[8] = {y0.x, y0.y, y0.z, y0.w, y1.x, y1.y, y1.z, y1.w};
            float r2[8] = {z0.x, z0.y, z0.z, z0.w, z1.x, z1.y, z1.z, z1.w};
            #pragma unroll
            for (int q = 0; q < 4; ++q) {
                float sel = (j0 + q < NWW) ? 1.f : 0.f;
                float v[9], vs[9];
                v[0] = r0[q]; v[1] = r0[q + 1]; v[2] = r0[q + 2];
                v[3] = r1[q]; v[4] = r1[q + 1]; v[5] = r1[q + 2];
                v[6] = r2[q]; v[7] = r2[q + 1]; v[8] = r2[q + 2];
                #pragma unroll
                for (int d = 0; d < 9; ++d) { vs[d] = v[d] * sel; sm[d] += vs[d]; }
                int k = 0;
                #pragma unroll
                for (int d = 0; d < 9; ++d)
                    #pragma unroll
                    for (int e = d; e < 9; ++e)
                        acc[k++] += vs[d] * v[e];
            }
        }
        #pragma unroll
        for (int k = 0; k < 45; ++k) {
            float x = acc[k];
            #pragma unroll
            for (int off = 32; off > 0; off >>= 1) x += __shfl_down(x, off);
            if (lane == 0) red[wave][k] = x;
        }
        float sred[9];
        #pragma unroll
        for (int k = 0; k < 9; ++k) {
            float x = sm[k];
            #pragma unroll
            for (int off = 32; off > 0; off >>= 1) x += __shfl_down(x, off);
            sred[k] = x;
        }
        if (lane == 0) {
            #pragma unroll
            for (int k = 0; k < 9; ++k) red[wave][45 + k] = sred[k];
        }
        __syncthreads();
        if (tid < 54) {
            float x = red[0][tid] + red[1][tid] + red[2][tid] + red[3][tid];
            int slot;
            if (tid < 45) slot = (mode == 0 ? 0 : 45) + tid;
            else          slot = (mode == 0 ? 171 : 180) + (tid - 45);
            partial[((size_t)ch * NSLOT + slot) * NCT + nc] = x;
        }
    } else {
        float acc[81];
        #pragma unroll
        for (int k = 0; k < 81; ++k) acc[k] = 0.f;

        const int items = rc * 43;
        for (int it = tid; it < items; it += 256) {
            int i  = rowbase + it / 43;
            int g  = it - (it / 43) * 43;
            int j0 = g * 4;
            const float* lp = Lb + (size_t)i * PSTR + j0;
            const float* pp = Pb + (size_t)i * PSTR + j0;
            float4 lx0 = *(const float4*)(lp);
            float4 lx1 = *(const float4*)(lp + 4);
            float4 ly0 = *(const float4*)(lp + PSTR);
            float4 ly1 = *(const float4*)(lp + PSTR + 4);
            float4 lz0 = *(const float4*)(lp + 2 * PSTR);
            float4 lz1 = *(const float4*)(lp + 2 * PSTR + 4);
            float4 px0 = *(const float4*)(pp);
            float4 px1 = *(const float4*)(pp + 4);
            float4 py0 = *(const float4*)(pp + PSTR);
            float4 py1 = *(const float4*)(pp + PSTR + 4);
            float4 pz0 = *(const float4*)(pp + 2 * PSTR);
            float4 pz1 = *(const float4*)(pp + 2 * PSTR + 4);
            float lr0[8] = {lx0.x, lx0.y, lx0.z, lx0.w, lx1.x, lx1.y, lx1.z, lx1.w};
            float lr1[8] = {ly0.x, ly0.y, ly0.z, ly0.w, ly1.x, ly1.y, ly1.z, ly1.w};
            float lr2[8] = {lz0.x, lz0.y, lz0.z, lz0.w, lz1.x, lz1.y, lz1.z, lz1.w};
            float pr0[8] = {px0.x, px0.y, px0.z, px0.w, px1.x, px1.y, px1.z, px1.w};
            float pr1[8] = {py0.x, py0.y, py0.z, py0.w, py1.x, py1.y, py1.z, py1.w};
            float pr2[8] = {pz0.x, pz0.y, pz0.z, pz0.w, pz1.x, pz1.y, pz1.z, pz1.w};
            #pragma unroll
            for (int q = 0; q < 4; ++q) {
                float sel = (j0 + q < NWW) ? 1.f : 0.f;
                float vl[9], vp[9];
                vl[0] = lr0[q] * sel; vl[1] = lr0[q + 1] * sel; vl[2] = lr0[q + 2] * sel;
                vl[3] = lr1[q] * sel; vl[4] = lr1[q + 1] * sel; vl[5] = lr1[q + 2] * sel;
                vl[6] = lr2[q] * sel; vl[7] = lr2[q + 1] * sel; vl[8] = lr2[q + 2] * sel;
                vp[0] = pr0[q]; vp[1] = pr0[q + 1]; vp[2] = pr0[q + 2];
                vp[3] = pr1[q]; vp[4] = pr1[q + 1]; vp[5] = pr1[q + 2];
                vp[6] = pr2[q]; vp[7] = pr2[q + 1]; vp[8] = pr2[q + 2];
                #pragma unroll
                for (int d = 0; d < 9; ++d)
                    #pragma unroll
                    for (int e = 0; e < 9; ++e)
                        acc[d * 9 + e] += vl[d] * vp[e];
            }
        }
        #pragma unroll
        for (int k = 0; k < 81; ++k) {
            float x = acc[k];
            #pragma unroll
            for (int off = 32; off > 0; off >>= 1) x += __shfl_down(x, off);
            if (lane == 0) red[wave][k] = x;
        }
        __syncthreads();
        if (tid < 81) {
            float x = red[0][tid] + red[1][tid] + red[2][tid] + red[3][tid];
            partial[((size_t)ch * NSLOT + 90 + tid) * NCT + nc] = x;
        }
    }
}

// ---------- Kernel D: cooperative per-(n,c) 9x9 algebra. One block per nc, LDS matrices. ----------
__global__ __launch_bounds__(128) void solve_kernel(const float* __restrict__ partial,
                                                    double* __restrict__ per_nc) {
    const int nc = blockIdx.x;
    const int tid = threadIdx.x;
    __shared__ double cl[45], cp[45], clp[81], sL[9], sP[9];
    __shared__ double All[81], C[81], Pm[81], X[81], A[81];
    __shared__ double logacc;

    // Phase 0: sum chunk partials (coalesced over nc across blocks' lanes)
    for (int s = tid; s < NSLOT; s += 128) {
        double acc = 0.0;
        for (int ch = 0; ch < NCHUNK; ++ch)
            acc += (double)partial[((size_t)ch * NSLOT + s) * NCT + nc];
        if (s < 45)       cl[s] = acc;
        else if (s < 90)  cp[s - 45] = acc;
        else if (s < 171) clp[s - 90] = acc;
        else if (s < 180) sL[s - 171] = acc;
        else              sP[s - 180] = acc;
    }
    if (tid == 0) logacc = 0.0;
    __syncthreads();

    // Phase 1: build All (la_cov), C (pr_cov + aI), Pm (la_pr_cov)
    const double M = (double)MPTS;
    if (tid < 81) {
        int d = tid / 9, e = tid % 9;
        int lo = d < e ? d : e, hi = d < e ? e : d;
        int k = 9 * lo - lo * (lo - 1) / 2 + (hi - lo);   // sym upper-tri index
        All[tid] = cl[k] - sL[d] * sL[e] / M;
        C[tid]   = cp[k] - sP[d] * sP[e] / M + (d == e ? 1e-3 : 0.0);
        Pm[tid]  = clp[tid] - sL[d] * sP[e] / M;
    }
    __syncthreads();

    // Phase 2: Cholesky of C (right-looking, lower, in place)
    for (int k = 0; k < 9; ++k) {
        if (tid == 0) C[k * 9 + k] = sqrt(fmax(C[k * 9 + k], 1e-30));
        __syncthreads();
        if (tid > k && tid < 9) C[tid * 9 + k] /= C[k * 9 + k];
        __syncthreads();
        if (tid < 81) {
            int i = tid / 9, j = tid % 9;
            if (j > k && i >= j) C[i * 9 + j] -= C[i * 9 + k] * C[j * 9 + k];
        }
        __syncthreads();
    }

    // Phase 3: forward substitution  G * X = Pm^T  (X[e][d], parallel over d)
    for (int e = 0; e < 9; ++e) {
        if (tid < 9) {
            int d = tid;
            double sum = Pm[d * 9 + e];
            for (int k = 0; k < e; ++k) sum -= C[e * 9 + k] * X[k * 9 + d];
            X[e * 9 + d] = sum / C[e * 9 + e];
        }
        __syncthreads();
    }

    // Phase 4: A = All - X^T X + alpha I
    if (tid < 81) {
        int d = tid / 9, g = tid % 9;
        double w = 0.0;
        #pragma unroll
        for (int e = 0; e < 9; ++e) w += X[e * 9 + d] * X[e * 9 + g];
        A[tid] = All[tid] - w + (d == g ? 1e-3 : 0.0);
    }
    __syncthreads();

    // Phase 5: Cholesky of A, accumulate log(diag + 1e-8)
    for (int k = 0; k < 9; ++k) {
        if (tid == 0) {
            double piv = sqrt(fmax(A[k * 9 + k], 0.0));
            A[k * 9 + k] = piv;
            logacc += log(piv + 1e-8);
        }
        __syncthreads();
        if (tid > k && tid < 9) A[tid * 9 + k] /= A[k * 9 + k];
        __syncthreads();
        if (tid < 81) {
            int i = tid / 9, j = tid % 9;
            if (j > k && i >= j) A[i * 9 + j] -= A[i * 9 + k] * A[j * 9 + k];
        }
        __syncthreads();
    }
    if (tid == 0) per_nc[nc] = logacc;
}

// ---------- Kernel E: final 104-way reduction ----------
__global__ __launch_bounds__(128) void reduce_kernel(const double* __restrict__ per_nc,
                                                     float* __restrict__ out) {
    int t = threadIdx.x;
    double r = (t < NCT) ? per_nc[t] : 0.0;
    __shared__ double red[128];
    red[t] = r;
    __syncthreads();
    for (int s = 64; s > 0; s >>= 1) {
        if (t < s) red[t] += red[t + s];
        __syncthreads();
    }
    if (t == 0) out[0] = (float)(red[0] / 36.0);  // mean over n(4) and /HALF_D(9)
}

extern "C" void kernel_launch(void* const* d_in, const int* in_sizes, int n_in,
                              void* d_out, int out_size, void* d_ws, size_t ws_size,
                              hipStream_t stream) {
    const float* cls  = (const float*)d_in[0];
    const float* tgt  = (const float*)d_in[1];
    const float* mask = (const float*)d_in[2];

    // ws layout (per_nc first for 8B alignment)
    double*       per_nc  = (double*)d_ws;                               // 104 (pad to 128)
    float*        aV      = (float*)(per_nc + 128);                      // 104*171*512 f32
    unsigned int* bV      = (unsigned int*)(aV + (size_t)NCT * PHH * WW);// 104*171*512 u8
    float*        poolL   = (float*)((char*)bV + (size_t)NCT * PHH * WW);
    float*        poolP   = poolL + (size_t)NCT * PHH * PSTR;
    float*        partial = poolP + (size_t)NCT * PHH * PSTR;            // NCHUNK*189*104

    const int nA = NCT * PHH * 128;
    vpool_kernel<<<(nA + 255) / 256, 256, 0, stream>>>(cls, tgt, mask, aV, bV);

    const int nB = NCT * PHH * PWW;
    hpool_kernel<<<(nB + 255) / 256, 256, 0, stream>>>(aV, (const unsigned char*)bV, poolL, poolP);

    dim3 gcov(NCT, 3, NCHUNK);
    cov_kernel<<<gcov, 256, 0, stream>>>(poolL, poolP, partial);

    solve_kernel<<<NCT, 128, 0, stream>>>(partial, per_nc);

    reduce_kernel<<<1, 128, 0, stream>>>(per_nc, (float*)d_out);
}

// Round 6
// 323.128 us; speedup vs baseline: 1.5703x; 1.1248x over previous
//
#include <hip/hip_runtime.h>
#include <math.h>

#define NUM_CLASSES 26
#define HH 512
#define WW 512
#define NB 4
#define PHH 171
#define PWW 171
#define NHH 169
#define NWW 169
#define MPTS (NHH*NWW)        // 28561
#define NCT (NB*NUM_CLASSES)  // 104
#define CLIPV 1e-6f
#define PSTR 176              // padded pool row stride
#define NCHUNK 4
#define ROWS_PER_CHUNK 43     // ceil(169/4)
#define NSLOT 189             // 45 covL + 45 covP + 81 covLP + 9 sumL + 9 sumP

// ---------- Kernel 1: fully fused maxpool (vertical+horizontal) + deferred sigmoid ----------
// One thread -> 4 pooled outputs. 16-col register tile, aligned float4 loads, no LDS/barriers.
__global__ __launch_bounds__(256, 4) void pool_kernel(const float* __restrict__ cls,
        const float* __restrict__ tgt, const float* __restrict__ mask,
        float* __restrict__ poolL, float* __restrict__ poolP) {
    const int total = NCT * PHH * 43;    // 43 quads of outputs per row
    for (int idx = blockIdx.x * 256 + threadIdx.x; idx < total; idx += gridDim.x * 256) {
        int t  = idx % 43;               // output quad: pw = 4t..4t+3
        int rr = idx / 43;
        int ph = rr % PHH;
        int nc = rr / PHH;
        int n  = nc / NUM_CLASSES;

        const float* clsB = cls  + (size_t)nc * HH * WW;
        const float* tgtB = tgt  + (size_t)nc * HH * WW;
        const float* mB   = mask + (size_t)n  * HH * WW;

        // register tile covers cols cb..cb+15 where cb = 12t-4 (16B aligned)
        float amax[16];
        #pragma unroll
        for (int i = 0; i < 16; ++i) amax[i] = -INFINITY;
        unsigned bbit = 0;

        const int f0 = (t == 0)  ? 1 : 0;   // skip cols < 0
        const int f1 = (t == 42) ? 3 : 4;   // skip cols >= 512
        const int r0 = 3 * ph - 1;
        #pragma unroll
        for (int s = 0; s < 3; ++s) {
            int r = r0 + s;
            if (r < 0) continue;             // only ph==0, s==0
            const float4* crow = (const float4*)(clsB + (size_t)r * WW) + (3 * t - 1);
            const float4* trow = (const float4*)(tgtB + (size_t)r * WW) + (3 * t - 1);
            const float4* mrow = (const float4*)(mB   + (size_t)r * WW) + (3 * t - 1);
            #pragma unroll
            for (int f = 0; f < 4; ++f) {
                if (f >= f0 && f < f1) {
                    float4 c = crow[f];
                    float4 g = trow[f];
                    float4 m = mrow[f];
                    float cc[4] = {c.x, c.y, c.z, c.w};
                    float gg[4] = {g.x, g.y, g.z, g.w};
                    float mm[4] = {m.x, m.y, m.z, m.w};
                    #pragma unroll
                    for (int k = 0; k < 4; ++k) {
                        int i = 4 * f + k;
                        amax[i] = fmaxf(amax[i], mm[k] > 0.5f ? cc[k] : -INFINITY);
                        bbit |= (gg[k] * mm[k] > 0.5f) ? (1u << i) : 0u;
                    }
                }
            }
        }
        // horizontal: output q uses tile slots 3q+3..3q+5
        float pout[4], lout[4];
        #pragma unroll
        for (int q = 0; q < 4; ++q) {
            float a = fmaxf(fmaxf(amax[3 * q + 3], amax[3 * q + 4]), amax[3 * q + 5]);
            int   b = (bbit >> (3 * q + 3)) & 7;
            pout[q] = __fdividef(1.0f, 1.0f + __expf(-a)) + CLIPV;  // a=-inf -> CLIP
            lout[q] = b ? 1.0f : 0.0f;
        }
        size_t o = ((size_t)nc * PHH + ph) * PSTR + 4 * t;
        *(float4*)(poolP + o) = make_float4(pout[0], pout[1], pout[2], pout[3]);
        *(float4*)(poolL + o) = make_float4(lout[0], lout[1], lout[2], lout[3]);
        if (t == 42) {   // zero pad cols 172..175 (cov reads 8-float spans into the pad)
            *(float4*)(poolP + o + 4) = make_float4(0.f, 0.f, 0.f, 0.f);
            *(float4*)(poolL + o + 4) = make_float4(0.f, 0.f, 0.f, 0.f);
        }
    }
}

// ---------- Kernel 2: covariance raw-sum partials ----------
// 4 modes, all <=54 accumulators (no spill): 0=LL(45+9), 1=PP(45+9), 2=LPa(d<5,45), 3=LPb(d>=5,36)
__global__ __launch_bounds__(256, 3) void cov_kernel(const float* __restrict__ poolL,
        const float* __restrict__ poolP, float* __restrict__ partial) {
    const int nc = blockIdx.x, mode = blockIdx.y, ch = blockIdx.z;
    const int tid = threadIdx.x, lane = tid & 63, wave = tid >> 6;
    const int rowbase = ch * ROWS_PER_CHUNK;
    const int rc = (rowbase + ROWS_PER_CHUNK <= NHH) ? ROWS_PER_CHUNK : (NHH - rowbase);
    const float* Lb = poolL + (size_t)nc * PHH * PSTR;
    const float* Pb = poolP + (size_t)nc * PHH * PSTR;
    const int items = rc * 43;

    __shared__ float red[4][54];

    if (mode < 2) {
        const float* src = mode ? Pb : Lb;
        float acc[45], sm[9];
        #pragma unroll
        for (int k = 0; k < 45; ++k) acc[k] = 0.f;
        #pragma unroll
        for (int k = 0; k < 9; ++k) sm[k] = 0.f;

        for (int it = tid; it < items; it += 256) {
            int i  = rowbase + it / 43;
            int j0 = (it - (it / 43) * 43) * 4;
            const float* rp = src + (size_t)i * PSTR + j0;
            float4 x0 = *(const float4*)(rp);
            float4 x1 = *(const float4*)(rp + 4);
            float4 y0 = *(const float4*)(rp + PSTR);
            float4 y1 = *(const float4*)(rp + PSTR + 4);
            float4 z0 = *(const float4*)(rp + 2 * PSTR);
            float4 z1 = *(const float4*)(rp + 2 * PSTR + 4);
            float r0[8] = {x0.x, x0.y, x0.z, x0.w, x1.x, x1.y, x1.z, x1.w};
            float r1[8] = {y0.x, y0.y, y0.z, y0.w, y1.x, y1.y, y1.z, y1.w};
            float r2[8] = {z0.x, z0.y, z0.z, z0.w, z1.x, z1.y, z1.z, z1.w};
            #pragma unroll
            for (int q = 0; q < 4; ++q) {
                float sel = (j0 + q < NWW) ? 1.f : 0.f;
                float v[9], vs[9];
                v[0] = r0[q]; v[1] = r0[q + 1]; v[2] = r0[q + 2];
                v[3] = r1[q]; v[4] = r1[q + 1]; v[5] = r1[q + 2];
                v[6] = r2[q]; v[7] = r2[q + 1]; v[8] = r2[q + 2];
                #pragma unroll
                for (int d = 0; d < 9; ++d) { vs[d] = v[d] * sel; sm[d] += vs[d]; }
                int k = 0;
                #pragma unroll
                for (int d = 0; d < 9; ++d)
                    #pragma unroll
                    for (int e = d; e < 9; ++e)
                        acc[k++] += vs[d] * v[e];
            }
        }
        #pragma unroll
        for (int k = 0; k < 45; ++k) {
            float x = acc[k];
            #pragma unroll
            for (int off = 32; off > 0; off >>= 1) x += __shfl_down(x, off);
            if (lane == 0) red[wave][k] = x;
        }
        #pragma unroll
        for (int k = 0; k < 9; ++k) {
            float x = sm[k];
            #pragma unroll
            for (int off = 32; off > 0; off >>= 1) x += __shfl_down(x, off);
            if (lane == 0) red[wave][45 + k] = x;
        }
        __syncthreads();
        if (tid < 54) {
            float x = red[0][tid] + red[1][tid] + red[2][tid] + red[3][tid];
            int slot = (tid < 45) ? (mode == 0 ? 0 : 45) + tid
                                  : (mode == 0 ? 171 : 180) + (tid - 45);
            partial[((size_t)ch * NSLOT + slot) * NCT + nc] = x;
        }
    } else {
        // LPa: d=0..4 (45 acc) ; LPb: d=5..8 (36 acc)
        const int nd  = (mode == 2) ? 5 : 4;
        const int dof = (mode == 2) ? 0 : 5;
        float acc[45];
        #pragma unroll
        for (int k = 0; k < 45; ++k) acc[k] = 0.f;

        for (int it = tid; it < items; it += 256) {
            int i  = rowbase + it / 43;
            int j0 = (it - (it / 43) * 43) * 4;
            const float* lp = Lb + (size_t)i * PSTR + j0;
            const float* pp = Pb + (size_t)i * PSTR + j0;
            float4 px0 = *(const float4*)(pp);
            float4 px1 = *(const float4*)(pp + 4);
            float4 py0 = *(const float4*)(pp + PSTR);
            float4 py1 = *(const float4*)(pp + PSTR + 4);
            float4 pz0 = *(const float4*)(pp + 2 * PSTR);
            float4 pz1 = *(const float4*)(pp + 2 * PSTR + 4);
            float pr0[8] = {px0.x, px0.y, px0.z, px0.w, px1.x, px1.y, px1.z, px1.w};
            float pr1[8] = {py0.x, py0.y, py0.z, py0.w, py1.x, py1.y, py1.z, py1.w};
            float pr2[8] = {pz0.x, pz0.y, pz0.z, pz0.w, pz1.x, pz1.y, pz1.z, pz1.w};
            // L rows needed: LPa -> rows i,i+1 ; LPb -> rows i+1,i+2
            const float* la = lp + (mode == 2 ? 0 : PSTR);
            const float* lb2 = lp + (mode == 2 ? PSTR : 2 * PSTR);
            float4 la0 = *(const float4*)(la);
            float4 la1 = *(const float4*)(la + 4);
            float4 lb0 = *(const float4*)(lb2);
            float4 lb1 = *(const float4*)(lb2 + 4);
            float lrA[8] = {la0.x, la0.y, la0.z, la0.w, la1.x, la1.y, la1.z, la1.w};
            float lrB[8] = {lb0.x, lb0.y, lb0.z, lb0.w, lb1.x, lb1.y, lb1.z, lb1.w};
            #pragma unroll
            for (int q = 0; q < 4; ++q) {
                float sel = (j0 + q < NWW) ? 1.f : 0.f;
                float vp[9];
                vp[0] = pr0[q]; vp[1] = pr0[q + 1]; vp[2] = pr0[q + 2];
                vp[3] = pr1[q]; vp[4] = pr1[q + 1]; vp[5] = pr1[q + 2];
                vp[6] = pr2[q]; vp[7] = pr2[q + 1]; vp[8] = pr2[q + 2];
                float vl[5];
                if (mode == 2) {
                    // d=0..2: row i cols q..q+2 ; d=3,4: row i+1 cols q..q+1
                    vl[0] = lrA[q] * sel; vl[1] = lrA[q + 1] * sel; vl[2] = lrA[q + 2] * sel;
                    vl[3] = lrB[q] * sel; vl[4] = lrB[q + 1] * sel;
                } else {
                    // d=5: row i+1 col q+2 ; d=6..8: row i+2 cols q..q+2
                    vl[0] = lrA[q + 2] * sel;
                    vl[1] = lrB[q] * sel; vl[2] = lrB[q + 1] * sel; vl[3] = lrB[q + 2] * sel;
                }
                #pragma unroll
                for (int d = 0; d < 5; ++d) {
                    if (d < nd) {
                        #pragma unroll
                        for (int e = 0; e < 9; ++e)
                            acc[d * 9 + e] += vl[d] * vp[e];
                    }
                }
            }
        }
        const int nred = nd * 9;
        #pragma unroll
        for (int k = 0; k < 45; ++k) {
            if (k < nred) {
                float x = acc[k];
                #pragma unroll
                for (int off = 32; off > 0; off >>= 1) x += __shfl_down(x, off);
                if (lane == 0) red[wave][k] = x;
            }
        }
        __syncthreads();
        if (tid < nred) {
            float x = red[0][tid] + red[1][tid] + red[2][tid] + red[3][tid];
            int slot = 90 + (dof * 9) + tid;    // clp slot = 90 + d*9 + e (linear)
            partial[((size_t)ch * NSLOT + slot) * NCT + nc] = x;
        }
    }
}

// ---------- Kernel 3: cooperative per-(n,c) 9x9 algebra ----------
__global__ __launch_bounds__(128) void solve_kernel(const float* __restrict__ partial,
                                                    double* __restrict__ per_nc) {
    const int nc = blockIdx.x;
    const int tid = threadIdx.x;
    __shared__ double cl[45], cp[45], clp[81], sL[9], sP[9];
    __shared__ double All[81], C[81], Pm[81], X[81], A[81];
    __shared__ double logacc;

    for (int s = tid; s < NSLOT; s += 128) {
        double acc = 0.0;
        for (int ch = 0; ch < NCHUNK; ++ch)
            acc += (double)partial[((size_t)ch * NSLOT + s) * NCT + nc];
        if (s < 45)       cl[s] = acc;
        else if (s < 90)  cp[s - 45] = acc;
        else if (s < 171) clp[s - 90] = acc;
        else if (s < 180) sL[s - 171] = acc;
        else              sP[s - 180] = acc;
    }
    if (tid == 0) logacc = 0.0;
    __syncthreads();

    const double M = (double)MPTS;
    if (tid < 81) {
        int d = tid / 9, e = tid % 9;
        int lo = d < e ? d : e, hi = d < e ? e : d;
        int k = 9 * lo - lo * (lo - 1) / 2 + (hi - lo);
        All[tid] = cl[k] - sL[d] * sL[e] / M;
        C[tid]   = cp[k] - sP[d] * sP[e] / M + (d == e ? 1e-3 : 0.0);
        Pm[tid]  = clp[tid] - sL[d] * sP[e] / M;
    }
    __syncthreads();

    for (int k = 0; k < 9; ++k) {
        if (tid == 0) C[k * 9 + k] = sqrt(fmax(C[k * 9 + k], 1e-30));
        __syncthreads();
        if (tid > k && tid < 9) C[tid * 9 + k] /= C[k * 9 + k];
        __syncthreads();
        if (tid < 81) {
            int i = tid / 9, j = tid % 9;
            if (j > k && i >= j) C[i * 9 + j] -= C[i * 9 + k] * C[j * 9 + k];
        }
        __syncthreads();
    }

    for (int e = 0; e < 9; ++e) {
        if (tid < 9) {
            int d = tid;
            double sum = Pm[d * 9 + e];
            for (int k = 0; k < e; ++k) sum -= C[e * 9 + k] * X[k * 9 + d];
            X[e * 9 + d] = sum / C[e * 9 + e];
        }
        __syncthreads();
    }

    if (tid < 81) {
        int d = tid / 9, g = tid % 9;
        double w = 0.0;
        #pragma unroll
        for (int e = 0; e < 9; ++e) w += X[e * 9 + d] * X[e * 9 + g];
        A[tid] = All[tid] - w + (d == g ? 1e-3 : 0.0);
    }
    __syncthreads();

    for (int k = 0; k < 9; ++k) {
        if (tid == 0) {
            double piv = sqrt(fmax(A[k * 9 + k], 0.0));
            A[k * 9 + k] = piv;
            logacc += log(piv + 1e-8);
        }
        __syncthreads();
        if (tid > k && tid < 9) A[tid * 9 + k] /= A[k * 9 + k];
        __syncthreads();
        if (tid < 81) {
            int i = tid / 9, j = tid % 9;
            if (j > k && i >= j) A[i * 9 + j] -= A[i * 9 + k] * A[j * 9 + k];
        }
        __syncthreads();
    }
    if (tid == 0) per_nc[nc] = logacc;
}

// ---------- Kernel 4: final reduction ----------
__global__ __launch_bounds__(128) void reduce_kernel(const double* __restrict__ per_nc,
                                                     float* __restrict__ out) {
    int t = threadIdx.x;
    double r = (t < NCT) ? per_nc[t] : 0.0;
    __shared__ double red[128];
    red[t] = r;
    __syncthreads();
    for (int s = 64; s > 0; s >>= 1) {
        if (t < s) red[t] += red[t + s];
        __syncthreads();
    }
    if (t == 0) out[0] = (float)(red[0] / 36.0);
}

extern "C" void kernel_launch(void* const* d_in, const int* in_sizes, int n_in,
                              void* d_out, int out_size, void* d_ws, size_t ws_size,
                              hipStream_t stream) {
    const float* cls  = (const float*)d_in[0];
    const float* tgt  = (const float*)d_in[1];
    const float* mask = (const float*)d_in[2];

    double* per_nc  = (double*)d_ws;                               // 128 doubles
    float*  poolL   = (float*)(per_nc + 128);
    float*  poolP   = poolL + (size_t)NCT * PHH * PSTR;
    float*  partial = poolP + (size_t)NCT * PHH * PSTR;            // NCHUNK*NSLOT*NCT

    pool_kernel<<<1024, 256, 0, stream>>>(cls, tgt, mask, poolL, poolP);

    dim3 gcov(NCT, 4, NCHUNK);
    cov_kernel<<<gcov, 256, 0, stream>>>(poolL, poolP, partial);

    solve_kernel<<<NCT, 128, 0, stream>>>(partial, per_nc);

    reduce_kernel<<<1, 128, 0, stream>>>(per_nc, (float*)d_out);
}

// Round 7
// 316.566 us; speedup vs baseline: 1.6029x; 1.0207x over previous
//
#include <hip/hip_runtime.h>
#include <math.h>

#define NUM_CLASSES 26
#define HH 512
#define WW 512
#define NB 4
#define PHH 171
#define PWW 171
#define NHH 169
#define NWW 169
#define MPTS (NHH*NWW)        // 28561
#define NCT (NB*NUM_CLASSES)  // 104
#define CLIPV 1e-6f
#define PSTR 176              // padded pool row stride
#define NCHUNK 8
#define ROWS_PER_CHUNK 22     // ceil(169/8)
#define NSLOT 189             // 45 covL + 45 covP + 81 covLP + 9 sumL + 9 sumP

// ---------- Kernel 1: per-wave fused maxpool + deferred sigmoid ----------
// One wave per pooled output row (nc, ph). Vertical max via coalesced float4
// loads -> registers -> LDS; horizontal stride-3 max from LDS (conflict-free);
// coalesced dword stores. One barrier.
__global__ __launch_bounds__(256) void pool_kernel(const float* __restrict__ cls,
        const float* __restrict__ tgt, const float* __restrict__ mask,
        float* __restrict__ poolL, float* __restrict__ poolP) {
    __shared__ float amax[4][512];
    __shared__ float lmax[4][512];
    const int w = threadIdx.x >> 6, lane = threadIdx.x & 63;
    const int R = blockIdx.x * 4 + w;          // 4446 blocks * 4 = 17784 = NCT*PHH exactly
    const int ph = R % PHH, nc = R / PHH, n = nc / NUM_CLASSES;

    const float4* c4 = (const float4*)(cls  + (size_t)nc * HH * WW);
    const float4* t4 = (const float4*)(tgt  + (size_t)nc * HH * WW);
    const float4* m4 = (const float4*)(mask + (size_t)n  * HH * WW);

    float am[8], lm[8];
    #pragma unroll
    for (int k = 0; k < 8; ++k) { am[k] = -INFINITY; lm[k] = 0.f; }

    const int r0 = 3 * ph - 1;
    const int s0 = (ph == 0) ? 1 : 0;          // r=-1 only possible at ph==0
    for (int s = s0; s < 3; ++s) {
        int rbase = (r0 + s) * 128;
        #pragma unroll
        for (int g = 0; g < 2; ++g) {
            int i4 = rbase + lane + 64 * g;
            float4 c = c4[i4];
            float4 t = t4[i4];
            float4 m = m4[i4];
            float cc[4] = {c.x, c.y, c.z, c.w};
            float tt[4] = {t.x, t.y, t.z, t.w};
            float mm[4] = {m.x, m.y, m.z, m.w};
            #pragma unroll
            for (int k = 0; k < 4; ++k) {
                int j = 4 * g + k;
                am[j] = fmaxf(am[j], mm[k] > 0.5f ? cc[k] : -INFINITY);
                lm[j] = fmaxf(lm[j], tt[k] * mm[k]);
            }
        }
    }
    // cols for g: 4*lane (g=0), 256+4*lane (g=1) — 16B-aligned b128 writes
    *(float4*)&amax[w][4 * lane]       = make_float4(am[0], am[1], am[2], am[3]);
    *(float4*)&amax[w][256 + 4 * lane] = make_float4(am[4], am[5], am[6], am[7]);
    *(float4*)&lmax[w][4 * lane]       = make_float4(lm[0], lm[1], lm[2], lm[3]);
    *(float4*)&lmax[w][256 + 4 * lane] = make_float4(lm[4], lm[5], lm[6], lm[7]);
    __syncthreads();

    const size_t rowo = (size_t)(nc * PHH + ph) * PSTR;
    #pragma unroll
    for (int j = 0; j < 3; ++j) {
        int pw = lane + 64 * j;
        if (pw < PWW) {
            int cM = 3 * pw;                    // window cols cM-1, cM, cM+1 (cM+1<=511)
            float a = fmaxf(amax[w][cM], amax[w][cM + 1]);
            float l = fmaxf(lmax[w][cM], lmax[w][cM + 1]);
            if (cM > 0) {
                a = fmaxf(a, amax[w][cM - 1]);
                l = fmaxf(l, lmax[w][cM - 1]);
            }
            poolP[rowo + pw] = __fdividef(1.0f, 1.0f + __expf(-a)) + CLIPV;
            poolL[rowo + pw] = (l > 0.5f) ? 1.0f : 0.0f;
        } else if (j == 2 && lane >= 43 && lane < 48) {
            int pc = 128 + lane;                // pad cols 171..175 -> zero
            poolP[rowo + pc] = 0.f;
            poolL[rowo + pc] = 0.f;
        }
    }
}

// ---------- Kernel 2: covariance raw-sum partials ----------
// 4 modes, all <=54 accumulators: 0=LL(45+9), 1=PP(45+9), 2=LPa(d<5,45), 3=LPb(d>=5,36)
__global__ __launch_bounds__(256, 4) void cov_kernel(const float* __restrict__ poolL,
        const float* __restrict__ poolP, float* __restrict__ partial) {
    const int nc = blockIdx.x, mode = blockIdx.y, ch = blockIdx.z;
    const int tid = threadIdx.x, lane = tid & 63, wave = tid >> 6;
    const int rowbase = ch * ROWS_PER_CHUNK;
    const int rc = (rowbase + ROWS_PER_CHUNK <= NHH) ? ROWS_PER_CHUNK : (NHH - rowbase);
    const float* Lb = poolL + (size_t)nc * PHH * PSTR;
    const float* Pb = poolP + (size_t)nc * PHH * PSTR;
    const int items = rc * 43;

    __shared__ float red[4][54];

    if (mode < 2) {
        const float* src = mode ? Pb : Lb;
        float acc[45], sm[9];
        #pragma unroll
        for (int k = 0; k < 45; ++k) acc[k] = 0.f;
        #pragma unroll
        for (int k = 0; k < 9; ++k) sm[k] = 0.f;

        for (int it = tid; it < items; it += 256) {
            int i  = rowbase + it / 43;
            int j0 = (it - (it / 43) * 43) * 4;
            const float* rp = src + (size_t)i * PSTR + j0;
            float4 x0 = *(const float4*)(rp);
            float4 x1 = *(const float4*)(rp + 4);
            float4 y0 = *(const float4*)(rp + PSTR);
            float4 y1 = *(const float4*)(rp + PSTR + 4);
            float4 z0 = *(const float4*)(rp + 2 * PSTR);
            float4 z1 = *(const float4*)(rp + 2 * PSTR + 4);
            float r0[8] = {x0.x, x0.y, x0.z, x0.w, x1.x, x1.y, x1.z, x1.w};
            float r1[8] = {y0.x, y0.y, y0.z, y0.w, y1.x, y1.y, y1.z, y1.w};
            float r2[8] = {z0.x, z0.y, z0.z, z0.w, z1.x, z1.y, z1.z, z1.w};
            #pragma unroll
            for (int q = 0; q < 4; ++q) {
                float sel = (j0 + q < NWW) ? 1.f : 0.f;
                float v[9], vs[9];
                v[0] = r0[q]; v[1] = r0[q + 1]; v[2] = r0[q + 2];
                v[3] = r1[q]; v[4] = r1[q + 1]; v[5] = r1[q + 2];
                v[6] = r2[q]; v[7] = r2[q + 1]; v[8] = r2[q + 2];
                #pragma unroll
                for (int d = 0; d < 9; ++d) { vs[d] = v[d] * sel; sm[d] += vs[d]; }
                int k = 0;
                #pragma unroll
                for (int d = 0; d < 9; ++d)
                    #pragma unroll
                    for (int e = d; e < 9; ++e)
                        acc[k++] += vs[d] * v[e];
            }
        }
        #pragma unroll
        for (int k = 0; k < 45; ++k) {
            float x = acc[k];
            #pragma unroll
            for (int off = 32; off > 0; off >>= 1) x += __shfl_down(x, off);
            if (lane == 0) red[wave][k] = x;
        }
        #pragma unroll
        for (int k = 0; k < 9; ++k) {
            float x = sm[k];
            #pragma unroll
            for (int off = 32; off > 0; off >>= 1) x += __shfl_down(x, off);
            if (lane == 0) red[wave][45 + k] = x;
        }
        __syncthreads();
        if (tid < 54) {
            float x = red[0][tid] + red[1][tid] + red[2][tid] + red[3][tid];
            int slot = (tid < 45) ? (mode == 0 ? 0 : 45) + tid
                                  : (mode == 0 ? 171 : 180) + (tid - 45);
            partial[((size_t)ch * NSLOT + slot) * NCT + nc] = x;
        }
    } else {
        const int nd  = (mode == 2) ? 5 : 4;
        const int dof = (mode == 2) ? 0 : 5;
        float acc[45];
        #pragma unroll
        for (int k = 0; k < 45; ++k) acc[k] = 0.f;

        for (int it = tid; it < items; it += 256) {
            int i  = rowbase + it / 43;
            int j0 = (it - (it / 43) * 43) * 4;
            const float* lp = Lb + (size_t)i * PSTR + j0;
            const float* pp = Pb + (size_t)i * PSTR + j0;
            float4 px0 = *(const float4*)(pp);
            float4 px1 = *(const float4*)(pp + 4);
            float4 py0 = *(const float4*)(pp + PSTR);
            float4 py1 = *(const float4*)(pp + PSTR + 4);
            float4 pz0 = *(const float4*)(pp + 2 * PSTR);
            float4 pz1 = *(const float4*)(pp + 2 * PSTR + 4);
            float pr0[8] = {px0.x, px0.y, px0.z, px0.w, px1.x, px1.y, px1.z, px1.w};
            float pr1[8] = {py0.x, py0.y, py0.z, py0.w, py1.x, py1.y, py1.z, py1.w};
            float pr2[8] = {pz0.x, pz0.y, pz0.z, pz0.w, pz1.x, pz1.y, pz1.z, pz1.w};
            const float* la  = lp + (mode == 2 ? 0 : PSTR);
            const float* lb2 = lp + (mode == 2 ? PSTR : 2 * PSTR);
            float4 la0 = *(const float4*)(la);
            float4 la1 = *(const float4*)(la + 4);
            float4 lb0 = *(const float4*)(lb2);
            float4 lb1 = *(const float4*)(lb2 + 4);
            float lrA[8] = {la0.x, la0.y, la0.z, la0.w, la1.x, la1.y, la1.z, la1.w};
            float lrB[8] = {lb0.x, lb0.y, lb0.z, lb0.w, lb1.x, lb1.y, lb1.z, lb1.w};
            #pragma unroll
            for (int q = 0; q < 4; ++q) {
                float sel = (j0 + q < NWW) ? 1.f : 0.f;
                float vp[9];
                vp[0] = pr0[q]; vp[1] = pr0[q + 1]; vp[2] = pr0[q + 2];
                vp[3] = pr1[q]; vp[4] = pr1[q + 1]; vp[5] = pr1[q + 2];
                vp[6] = pr2[q]; vp[7] = pr2[q + 1]; vp[8] = pr2[q + 2];
                float vl[5];
                if (mode == 2) {
                    vl[0] = lrA[q] * sel; vl[1] = lrA[q + 1] * sel; vl[2] = lrA[q + 2] * sel;
                    vl[3] = lrB[q] * sel; vl[4] = lrB[q + 1] * sel;
                } else {
                    vl[0] = lrA[q + 2] * sel;
                    vl[1] = lrB[q] * sel; vl[2] = lrB[q + 1] * sel; vl[3] = lrB[q + 2] * sel;
                }
                #pragma unroll
                for (int d = 0; d < 5; ++d) {
                    if (d < nd) {
                        #pragma unroll
                        for (int e = 0; e < 9; ++e)
                            acc[d * 9 + e] += vl[d] * vp[e];
                    }
                }
            }
        }
        const int nred = nd * 9;
        #pragma unroll
        for (int k = 0; k < 45; ++k) {
            if (k < nred) {
                float x = acc[k];
                #pragma unroll
                for (int off = 32; off > 0; off >>= 1) x += __shfl_down(x, off);
                if (lane == 0) red[wave][k] = x;
            }
        }
        __syncthreads();
        if (tid < nred) {
            float x = red[0][tid] + red[1][tid] + red[2][tid] + red[3][tid];
            int slot = 90 + (dof * 9) + tid;
            partial[((size_t)ch * NSLOT + slot) * NCT + nc] = x;
        }
    }
}

// ---------- Kernel 3: cooperative per-(n,c) 9x9 algebra ----------
__global__ __launch_bounds__(128) void solve_kernel(const float* __restrict__ partial,
                                                    double* __restrict__ per_nc) {
    const int nc = blockIdx.x;
    const int tid = threadIdx.x;
    __shared__ double cl[45], cp[45], clp[81], sL[9], sP[9];
    __shared__ double All[81], C[81], Pm[81], X[81], A[81];
    __shared__ double logacc;

    for (int s = tid; s < NSLOT; s += 128) {
        double acc = 0.0;
        for (int ch = 0; ch < NCHUNK; ++ch)
            acc += (double)partial[((size_t)ch * NSLOT + s) * NCT + nc];
        if (s < 45)       cl[s] = acc;
        else if (s < 90)  cp[s - 45] = acc;
        else if (s < 171) clp[s - 90] = acc;
        else if (s < 180) sL[s - 171] = acc;
        else              sP[s - 180] = acc;
    }
    if (tid == 0) logacc = 0.0;
    __syncthreads();

    const double M = (double)MPTS;
    if (tid < 81) {
        int d = tid / 9, e = tid % 9;
        int lo = d < e ? d : e, hi = d < e ? e : d;
        int k = 9 * lo - lo * (lo - 1) / 2 + (hi - lo);
        All[tid] = cl[k] - sL[d] * sL[e] / M;
        C[tid]   = cp[k] - sP[d] * sP[e] / M + (d == e ? 1e-3 : 0.0);
        Pm[tid]  = clp[tid] - sL[d] * sP[e] / M;
    }
    __syncthreads();

    for (int k = 0; k < 9; ++k) {
        if (tid == 0) C[k * 9 + k] = sqrt(fmax(C[k * 9 + k], 1e-30));
        __syncthreads();
        if (tid > k && tid < 9) C[tid * 9 + k] /= C[k * 9 + k];
        __syncthreads();
        if (tid < 81) {
            int i = tid / 9, j = tid % 9;
            if (j > k && i >= j) C[i * 9 + j] -= C[i * 9 + k] * C[j * 9 + k];
        }
        __syncthreads();
    }

    for (int e = 0; e < 9; ++e) {
        if (tid < 9) {
            int d = tid;
            double sum = Pm[d * 9 + e];
            for (int k = 0; k < e; ++k) sum -= C[e * 9 + k] * X[k * 9 + d];
            X[e * 9 + d] = sum / C[e * 9 + e];
        }
        __syncthreads();
    }

    if (tid < 81) {
        int d = tid / 9, g = tid % 9;
        double w = 0.0;
        #pragma unroll
        for (int e = 0; e < 9; ++e) w += X[e * 9 + d] * X[e * 9 + g];
        A[tid] = All[tid] - w + (d == g ? 1e-3 : 0.0);
    }
    __syncthreads();

    for (int k = 0; k < 9; ++k) {
        if (tid == 0) {
            double piv = sqrt(fmax(A[k * 9 + k], 0.0));
            A[k * 9 + k] = piv;
            logacc += log(piv + 1e-8);
        }
        __syncthreads();
        if (tid > k && tid < 9) A[tid * 9 + k] /= A[k * 9 + k];
        __syncthreads();
        if (tid < 81) {
            int i = tid / 9, j = tid % 9;
            if (j > k && i >= j) A[i * 9 + j] -= A[i * 9 + k] * A[j * 9 + k];
        }
        __syncthreads();
    }
    if (tid == 0) per_nc[nc] = logacc;
}

// ---------- Kernel 4: final reduction ----------
__global__ __launch_bounds__(128) void reduce_kernel(const double* __restrict__ per_nc,
                                                     float* __restrict__ out) {
    int t = threadIdx.x;
    double r = (t < NCT) ? per_nc[t] : 0.0;
    __shared__ double red[128];
    red[t] = r;
    __syncthreads();
    for (int s = 64; s > 0; s >>= 1) {
        if (t < s) red[t] += red[t + s];
        __syncthreads();
    }
    if (t == 0) out[0] = (float)(red[0] / 36.0);
}

extern "C" void kernel_launch(void* const* d_in, const int* in_sizes, int n_in,
                              void* d_out, int out_size, void* d_ws, size_t ws_size,
                              hipStream_t stream) {
    const float* cls  = (const float*)d_in[0];
    const float* tgt  = (const float*)d_in[1];
    const float* mask = (const float*)d_in[2];

    double* per_nc  = (double*)d_ws;                               // 128 doubles
    float*  poolL   = (float*)(per_nc + 128);
    float*  poolP   = poolL + (size_t)NCT * PHH * PSTR;
    float*  partial = poolP + (size_t)NCT * PHH * PSTR;            // NCHUNK*NSLOT*NCT

    pool_kernel<<<NCT * PHH / 4, 256, 0, stream>>>(cls, tgt, mask, poolL, poolP);

    dim3 gcov(NCT, 4, NCHUNK);
    cov_kernel<<<gcov, 256, 0, stream>>>(poolL, poolP, partial);

    solve_kernel<<<NCT, 128, 0, stream>>>(partial, per_nc);

    reduce_kernel<<<1, 128, 0, stream>>>(per_nc, (float*)d_out);
}

// Round 8
// 277.995 us; speedup vs baseline: 1.8252x; 1.1387x over previous
//
#include <hip/hip_runtime.h>
#include <math.h>

#define NUM_CLASSES 26
#define HH 512
#define WW 512
#define NB 4
#define PHH 171
#define PWW 171
#define NHH 169
#define NWW 169
#define MPTS (NHH*NWW)        // 28561
#define NCT (NB*NUM_CLASSES)  // 104
#define CLIPV 1e-6f
#define NCHUNK 8
#define RPC 22                // rows per chunk (last: 15)
#define NSLOT 189             // 45 covL + 45 covP + 81 covLP + 9 sumL + 9 sumP

// ---------- Kernel 1: fused maxpool + covariance partials ----------
// grid (nc, chunk). Phase 1: pool rows rowbase..rowbase+rc+1 into LDS tile
// (per-wave vertical max -> wave-private scratch -> horizontal max, no barrier).
// Phase 2: wave w computes mode w (0=LL+sumL, 1=PP+sumP, 2=LPa d<5, 3=LPb d>=5).
__global__ __launch_bounds__(256, 3) void fused_kernel(const float* __restrict__ cls,
        const float* __restrict__ tgt, const float* __restrict__ mask,
        float* __restrict__ partial) {
    const int nc = blockIdx.x, ch = blockIdx.y;
    const int n = nc / NUM_CLASSES;
    const int lane = threadIdx.x & 63, wave = threadIdx.x >> 6;
    const int rowbase = ch * RPC;
    const int rc = (rowbase + RPC <= NHH) ? RPC : (NHH - rowbase);
    const int trows = rc + 2;     // pooled rows needed (<=24); ph max = 170

    __shared__ float tP[24][176];
    __shared__ float tL[24][176];
    __shared__ float amS[4][512];
    __shared__ float lmS[4][512];

    const float4* c4 = (const float4*)(cls  + (size_t)nc * HH * WW);
    const float4* t4 = (const float4*)(tgt  + (size_t)nc * HH * WW);
    const float4* m4 = (const float4*)(mask + (size_t)n  * HH * WW);

    // ---- Phase 1: pooled rows into tile ----
    for (int k = 0; k < 6; ++k) {
        int tr = wave + 4 * k;               // wave-uniform
        if (tr >= trows) break;
        int ph = rowbase + tr;
        float am[8], lm[8];
        #pragma unroll
        for (int j = 0; j < 8; ++j) { am[j] = -INFINITY; lm[j] = 0.f; }
        const int r0 = 3 * ph - 1;
        #pragma unroll
        for (int s = 0; s < 3; ++s) {
            int r = r0 + s;
            r = r < 0 ? 0 : r;               // ph==0: duplicate row 0 (max-idempotent)
            int rb = r * 128;
            #pragma unroll
            for (int g = 0; g < 2; ++g) {
                int i4 = rb + lane + 64 * g;
                float4 c = c4[i4];
                float4 t = t4[i4];
                float4 m = m4[i4];
                float cc[4] = {c.x, c.y, c.z, c.w};
                float tt[4] = {t.x, t.y, t.z, t.w};
                float mm[4] = {m.x, m.y, m.z, m.w};
                #pragma unroll
                for (int q = 0; q < 4; ++q) {
                    int j = 4 * g + q;
                    am[j] = fmaxf(am[j], mm[q] > 0.5f ? cc[q] : -INFINITY);
                    lm[j] = fmaxf(lm[j], tt[q] * mm[q]);
                }
            }
        }
        // cols 4*lane..4*lane+3 (g=0) and 256+4*lane.. (g=1)
        *(float4*)&amS[wave][4 * lane]       = make_float4(am[0], am[1], am[2], am[3]);
        *(float4*)&amS[wave][256 + 4 * lane] = make_float4(am[4], am[5], am[6], am[7]);
        *(float4*)&lmS[wave][4 * lane]       = make_float4(lm[0], lm[1], lm[2], lm[3]);
        *(float4*)&lmS[wave][256 + 4 * lane] = make_float4(lm[4], lm[5], lm[6], lm[7]);
        // same wave reads its own scratch: compiler inserts lgkmcnt wait, no barrier
        #pragma unroll
        for (int j = 0; j < 3; ++j) {
            int pw = lane + 64 * j;
            if (pw < PWW) {
                int cM = 3 * pw;             // window cols cM-1..cM+1 (cM+1<=511)
                float a = fmaxf(amS[wave][cM], amS[wave][cM + 1]);
                float l = fmaxf(lmS[wave][cM], lmS[wave][cM + 1]);
                if (cM > 0) {
                    a = fmaxf(a, amS[wave][cM - 1]);
                    l = fmaxf(l, lmS[wave][cM - 1]);
                }
                tP[tr][pw] = __fdividef(1.0f, 1.0f + __expf(-a)) + CLIPV;
                tL[tr][pw] = (l > 0.5f) ? 1.0f : 0.0f;
            }
        }
        if (lane < 5) {                      // zero pad cols 171..175
            tP[tr][171 + lane] = 0.f;
            tL[tr][171 + lane] = 0.f;
        }
    }
    __syncthreads();

    // ---- Phase 2: wave = mode ----
    const int items = rc * 43;
    float* pbase = partial + (size_t)ch * NSLOT * NCT + nc;

    if (wave < 2) {
        const float (*src)[176] = wave ? tP : tL;
        float acc[45], sm[9];
        #pragma unroll
        for (int k = 0; k < 45; ++k) acc[k] = 0.f;
        #pragma unroll
        for (int k = 0; k < 9; ++k) sm[k] = 0.f;

        for (int it = lane; it < items; it += 64) {
            int tr = it / 43;
            int j0 = (it - tr * 43) * 4;
            const float* rp = &src[tr][j0];
            float4 x0 = *(const float4*)(rp);
            float4 x1 = *(const float4*)(rp + 4);
            float4 y0 = *(const float4*)(rp + 176);
            float4 y1 = *(const float4*)(rp + 180);
            float4 z0 = *(const float4*)(rp + 352);
            float4 z1 = *(const float4*)(rp + 356);
            float r0[8] = {x0.x, x0.y, x0.z, x0.w, x1.x, x1.y, x1.z, x1.w};
            float r1[8] = {y0.x, y0.y, y0.z, y0.w, y1.x, y1.y, y1.z, y1.w};
            float r2[8] = {z0.x, z0.y, z0.z, z0.w, z1.x, z1.y, z1.z, z1.w};
            #pragma unroll
            for (int q = 0; q < 4; ++q) {
                float sel = (j0 + q < NWW) ? 1.f : 0.f;
                float v[9], vs[9];
                v[0] = r0[q]; v[1] = r0[q + 1]; v[2] = r0[q + 2];
                v[3] = r1[q]; v[4] = r1[q + 1]; v[5] = r1[q + 2];
                v[6] = r2[q]; v[7] = r2[q + 1]; v[8] = r2[q + 2];
                #pragma unroll
                for (int d = 0; d < 9; ++d) { vs[d] = v[d] * sel; sm[d] += vs[d]; }
                int k = 0;
                #pragma unroll
                for (int d = 0; d < 9; ++d)
                    #pragma unroll
                    for (int e = d; e < 9; ++e)
                        acc[k++] += vs[d] * v[e];
            }
        }
        #pragma unroll
        for (int k = 0; k < 45; ++k) {
            float x = acc[k];
            #pragma unroll
            for (int off = 32; off > 0; off >>= 1) x += __shfl_down(x, off);
            if (lane == 0) pbase[(size_t)((wave == 0 ? 0 : 45) + k) * NCT] = x;
        }
        #pragma unroll
        for (int k = 0; k < 9; ++k) {
            float x = sm[k];
            #pragma unroll
            for (int off = 32; off > 0; off >>= 1) x += __shfl_down(x, off);
            if (lane == 0) pbase[(size_t)((wave == 0 ? 171 : 180) + k) * NCT] = x;
        }
    } else {
        // LPa (wave 2): d=0..4 ; LPb (wave 3): d=5..8
        const int nd  = (wave == 2) ? 5 : 4;
        const int dof = (wave == 2) ? 0 : 5;
        float acc[45];
        #pragma unroll
        for (int k = 0; k < 45; ++k) acc[k] = 0.f;

        for (int it = lane; it < items; it += 64) {
            int tr = it / 43;
            int j0 = (it - tr * 43) * 4;
            const float* pp = &tP[tr][j0];
            float4 px0 = *(const float4*)(pp);
            float4 px1 = *(const float4*)(pp + 4);
            float4 py0 = *(const float4*)(pp + 176);
            float4 py1 = *(const float4*)(pp + 180);
            float4 pz0 = *(const float4*)(pp + 352);
            float4 pz1 = *(const float4*)(pp + 356);
            float pr0[8] = {px0.x, px0.y, px0.z, px0.w, px1.x, px1.y, px1.z, px1.w};
            float pr1[8] = {py0.x, py0.y, py0.z, py0.w, py1.x, py1.y, py1.z, py1.w};
            float pr2[8] = {pz0.x, pz0.y, pz0.z, pz0.w, pz1.x, pz1.y, pz1.z, pz1.w};
            const float* la  = &tL[tr + (wave == 2 ? 0 : 1)][j0];
            const float* lb2 = &tL[tr + (wave == 2 ? 1 : 2)][j0];
            float4 la0 = *(const float4*)(la);
            float4 la1 = *(const float4*)(la + 4);
            float4 lb0 = *(const float4*)(lb2);
            float4 lb1 = *(const float4*)(lb2 + 4);
            float lrA[8] = {la0.x, la0.y, la0.z, la0.w, la1.x, la1.y, la1.z, la1.w};
            float lrB[8] = {lb0.x, lb0.y, lb0.z, lb0.w, lb1.x, lb1.y, lb1.z, lb1.w};
            #pragma unroll
            for (int q = 0; q < 4; ++q) {
                float sel = (j0 + q < NWW) ? 1.f : 0.f;
                float vp[9];
                vp[0] = pr0[q]; vp[1] = pr0[q + 1]; vp[2] = pr0[q + 2];
                vp[3] = pr1[q]; vp[4] = pr1[q + 1]; vp[5] = pr1[q + 2];
                vp[6] = pr2[q]; vp[7] = pr2[q + 1]; vp[8] = pr2[q + 2];
                float vl[5];
                if (wave == 2) {
                    vl[0] = lrA[q] * sel; vl[1] = lrA[q + 1] * sel; vl[2] = lrA[q + 2] * sel;
                    vl[3] = lrB[q] * sel; vl[4] = lrB[q + 1] * sel;
                } else {
                    vl[0] = lrA[q + 2] * sel;
                    vl[1] = lrB[q] * sel; vl[2] = lrB[q + 1] * sel; vl[3] = lrB[q + 2] * sel;
                }
                #pragma unroll
                for (int d = 0; d < 5; ++d) {
                    if (d < nd) {
                        #pragma unroll
                        for (int e = 0; e < 9; ++e)
                            acc[d * 9 + e] += vl[d] * vp[e];
                    }
                }
            }
        }
        const int nred = nd * 9;
        #pragma unroll
        for (int k = 0; k < 45; ++k) {
            if (k < nred) {
                float x = acc[k];
                #pragma unroll
                for (int off = 32; off > 0; off >>= 1) x += __shfl_down(x, off);
                if (lane == 0) pbase[(size_t)(90 + dof * 9 + k) * NCT] = x;
            }
        }
    }
}

// ---------- Kernel 2: cooperative per-(n,c) 9x9 algebra ----------
__global__ __launch_bounds__(128) void solve_kernel(const float* __restrict__ partial,
                                                    double* __restrict__ per_nc) {
    const int nc = blockIdx.x;
    const int tid = threadIdx.x;
    __shared__ double cl[45], cp[45], clp[81], sL[9], sP[9];
    __shared__ double All[81], C[81], Pm[81], X[81], A[81];
    __shared__ double logacc;

    for (int s = tid; s < NSLOT; s += 128) {
        double acc = 0.0;
        for (int ch = 0; ch < NCHUNK; ++ch)
            acc += (double)partial[((size_t)ch * NSLOT + s) * NCT + nc];
        if (s < 45)       cl[s] = acc;
        else if (s < 90)  cp[s - 45] = acc;
        else if (s < 171) clp[s - 90] = acc;
        else if (s < 180) sL[s - 171] = acc;
        else              sP[s - 180] = acc;
    }
    if (tid == 0) logacc = 0.0;
    __syncthreads();

    const double M = (double)MPTS;
    if (tid < 81) {
        int d = tid / 9, e = tid % 9;
        int lo = d < e ? d : e, hi = d < e ? e : d;
        int k = 9 * lo - lo * (lo - 1) / 2 + (hi - lo);
        All[tid] = cl[k] - sL[d] * sL[e] / M;
        C[tid]   = cp[k] - sP[d] * sP[e] / M + (d == e ? 1e-3 : 0.0);
        Pm[tid]  = clp[tid] - sL[d] * sP[e] / M;
    }
    __syncthreads();

    for (int k = 0; k < 9; ++k) {
        if (tid == 0) C[k * 9 + k] = sqrt(fmax(C[k * 9 + k], 1e-30));
        __syncthreads();
        if (tid > k && tid < 9) C[tid * 9 + k] /= C[k * 9 + k];
        __syncthreads();
        if (tid < 81) {
            int i = tid / 9, j = tid % 9;
            if (j > k && i >= j) C[i * 9 + j] -= C[i * 9 + k] * C[j * 9 + k];
        }
        __syncthreads();
    }

    for (int e = 0; e < 9; ++e) {
        if (tid < 9) {
            int d = tid;
            double sum = Pm[d * 9 + e];
            for (int k = 0; k < e; ++k) sum -= C[e * 9 + k] * X[k * 9 + d];
            X[e * 9 + d] = sum / C[e * 9 + e];
        }
        __syncthreads();
    }

    if (tid < 81) {
        int d = tid / 9, g = tid % 9;
        double w = 0.0;
        #pragma unroll
        for (int e = 0; e < 9; ++e) w += X[e * 9 + d] * X[e * 9 + g];
        A[tid] = All[tid] - w + (d == g ? 1e-3 : 0.0);
    }
    __syncthreads();

    for (int k = 0; k < 9; ++k) {
        if (tid == 0) {
            double piv = sqrt(fmax(A[k * 9 + k], 0.0));
            A[k * 9 + k] = piv;
            logacc += log(piv + 1e-8);
        }
        __syncthreads();
        if (tid > k && tid < 9) A[tid * 9 + k] /= A[k * 9 + k];
        __syncthreads();
        if (tid < 81) {
            int i = tid / 9, j = tid % 9;
            if (j > k && i >= j) A[i * 9 + j] -= A[i * 9 + k] * A[j * 9 + k];
        }
        __syncthreads();
    }
    if (tid == 0) per_nc[nc] = logacc;
}

// ---------- Kernel 3: final reduction ----------
__global__ __launch_bounds__(128) void reduce_kernel(const double* __restrict__ per_nc,
                                                     float* __restrict__ out) {
    int t = threadIdx.x;
    double r = (t < NCT) ? per_nc[t] : 0.0;
    __shared__ double red[128];
    red[t] = r;
    __syncthreads();
    for (int s = 64; s > 0; s >>= 1) {
        if (t < s) red[t] += red[t + s];
        __syncthreads();
    }
    if (t == 0) out[0] = (float)(red[0] / 36.0);
}

extern "C" void kernel_launch(void* const* d_in, const int* in_sizes, int n_in,
                              void* d_out, int out_size, void* d_ws, size_t ws_size,
                              hipStream_t stream) {
    const float* cls  = (const float*)d_in[0];
    const float* tgt  = (const float*)d_in[1];
    const float* mask = (const float*)d_in[2];

    double* per_nc  = (double*)d_ws;                     // 128 doubles
    float*  partial = (float*)(per_nc + 128);            // NCHUNK*NSLOT*NCT floats

    dim3 gfused(NCT, NCHUNK);
    fused_kernel<<<gfused, 256, 0, stream>>>(cls, tgt, mask, partial);

    solve_kernel<<<NCT, 128, 0, stream>>>(partial, per_nc);

    reduce_kernel<<<1, 128, 0, stream>>>(per_nc, (float*)d_out);
}